// Round 9
// baseline (267.836 us; speedup 1.0000x reference)
//
#include <hip/hip_runtime.h>
#include <hip/hip_cooperative_groups.h>

namespace cg = cooperative_groups;

#define N_NODES 50000
#define N_EDGES 800000
#define IN_CH 128
#define OUT_CH 64
#define HEADS 8
#define ROW 512           // OUT_CH*HEADS, floats per output row
#define NBLK_G 782        // ceil(N_NODES / 64) gemm tiles
#define NBLK_A 782        // ceil(N_EDGES/4 / 256) bin blocks (200000 int4-groups)
#define NBIN 196          // dst>>8 bins (dst<50000 -> bin 0..195), 256 dsts/bin
#define BINCAP 4608       // per-bin edge capacity; load is Binom(800k,256/50k)=4082 mean, 6.5-sigma pad
#define MAXDEG 64         // padded bucket; P(deg>=64) ~ 1e-13 for B(800k,1/50k)
#define WS_STRIDE 136     // shorts per LDS row: 128 + 8 pad (272B, 16B-aligned)

typedef float f4 __attribute__((ext_vector_type(4)));
typedef short bf16x8 __attribute__((ext_vector_type(8)));

__device__ __forceinline__ float lrelu(float z) {
    return z > 0.0f ? z : 0.2f * z;
}

// fp32 -> bf16 (RNE) as raw 16-bit
__device__ __forceinline__ unsigned f2b(float f) {
    unsigned u = __float_as_uint(f);
    return (u + 0x7FFFu + ((u >> 16) & 1u)) >> 16;
}

// Fused kernel, parity-interleaved roles (R5: gemm and binning are
// independent; even blocks do a gemm tile, odd blocks a bin block, so
// every CU co-hosts compute-heavy and latency-bound waves and the bin
// stalls hide under MFMA/VALU).
__global__ __launch_bounds__(256) void gemm_bin(const float* __restrict__ x,
                                                const float* __restrict__ W,
                                                const float* __restrict__ attn,
                                                const int4* __restrict__ ei4,
                                                const int4* __restrict__ ej4,
                                                unsigned short* __restrict__ hbuf,
                                                float* __restrict__ s,
                                                float* __restrict__ t,
                                                int* __restrict__ bin_count,
                                                unsigned* __restrict__ binned) {
    __shared__ unsigned short xs[64 * WS_STRIDE];   // 17.4 KB, x tile in bf16
    __shared__ unsigned short wls[64 * WS_STRIDE];  // 17.4 KB, W^T in bf16
    const int tid = threadIdx.x;
    const int bid = blockIdx.x;

    if (bid & 1) {
        // ---------------- bin role (odd blocks) ----------------
        unsigned* hist = (unsigned*)xs;      // overlay: 3*196*4B = 2.4 KB
        unsigned* bse  = hist + NBIN;
        unsigned* cur  = bse + NBIN;
        if (tid < NBIN) { hist[tid] = 0u; cur[tid] = 0u; }
        __syncthreads();
        const int g = (bid >> 1) * 256 + tid;   // int4-group id
        const bool act = g < N_EDGES / 4;
        int4 li = make_int4(0, 0, 0, 0), lj = make_int4(0, 0, 0, 0);
        if (act) {
            li = ei4[g];
            lj = ej4[g];
            atomicAdd(&hist[li.x >> 8], 1u);
            atomicAdd(&hist[li.y >> 8], 1u);
            atomicAdd(&hist[li.z >> 8], 1u);
            atomicAdd(&hist[li.w >> 8], 1u);
        }
        __syncthreads();
        if (tid < NBIN) {
            const unsigned c = hist[tid];
            bse[tid] = c ? (unsigned)atomicAdd(&bin_count[tid], (int)c) : 0u;
        }
        __syncthreads();
        if (act) {
            const unsigned p0 = bse[li.x >> 8] + atomicAdd(&cur[li.x >> 8], 1u);
            if (p0 < BINCAP) binned[(li.x >> 8) * BINCAP + p0] =
                ((unsigned)(li.x & 255) << 16) | (unsigned)lj.x;
            const unsigned p1 = bse[li.y >> 8] + atomicAdd(&cur[li.y >> 8], 1u);
            if (p1 < BINCAP) binned[(li.y >> 8) * BINCAP + p1] =
                ((unsigned)(li.y & 255) << 16) | (unsigned)lj.y;
            const unsigned p2 = bse[li.z >> 8] + atomicAdd(&cur[li.z >> 8], 1u);
            if (p2 < BINCAP) binned[(li.z >> 8) * BINCAP + p2] =
                ((unsigned)(li.z & 255) << 16) | (unsigned)lj.z;
            const unsigned p3 = bse[li.w >> 8] + atomicAdd(&cur[li.w >> 8], 1u);
            if (p3 < BINCAP) binned[(li.w >> 8) * BINCAP + p3] =
                ((unsigned)(li.w & 255) << 16) | (unsigned)lj.w;
        }
        return;
    }

    // ---------------- gemm role (even blocks) ----------------
    const int base = (bid >> 1) * 64;
    {   // stage W transposed -> bf16: wls[col][k]
        const float4* W4 = (const float4*)W;
#pragma unroll
        for (int j = 0; j < 8; ++j) {
            const int idx = tid + j * 256;   // float4 index into [128][16]
            const int k = idx >> 4;
            const int c = (idx & 15) * 4;
            const float4 v = W4[idx];
            wls[(c + 0) * WS_STRIDE + k] = (unsigned short)f2b(v.x);
            wls[(c + 1) * WS_STRIDE + k] = (unsigned short)f2b(v.y);
            wls[(c + 2) * WS_STRIDE + k] = (unsigned short)f2b(v.z);
            wls[(c + 3) * WS_STRIDE + k] = (unsigned short)f2b(v.w);
        }
    }
    {   // stage x tile as bf16 (RNE at staging — same values as before)
        const float4* x4 = (const float4*)x;
#pragma unroll
        for (int j = 0; j < 8; ++j) {
            const int idx = tid + j * 256;   // float4 index into [64][32]
            const int r = idx >> 5;
            const int kq = idx & 31;
            const int row = base + r;
            float4 v = make_float4(0.f, 0.f, 0.f, 0.f);
            if (row < N_NODES) v = x4[row * 32 + kq];
            ushort4 pb;
            pb.x = (unsigned short)f2b(v.x);
            pb.y = (unsigned short)f2b(v.y);
            pb.z = (unsigned short)f2b(v.z);
            pb.w = (unsigned short)f2b(v.w);
            *(ushort4*)&xs[r * WS_STRIDE + kq * 4] = pb;
        }
    }
    __syncthreads();
    const int w = tid >> 6, lane = tid & 63;
    const int m = lane & 15;       // A row / B-C col within tile
    const int kq = lane >> 4;      // k-chunk quad / C row-quad
    bf16x8 afr[4];
#pragma unroll
    for (int kb = 0; kb < 4; ++kb)
        afr[kb] = *(const bf16x8*)&xs[(w * 16 + m) * WS_STRIDE + kb * 32 + kq * 8];
    float sacc[4] = {0.f, 0.f, 0.f, 0.f};
    float tacc[4] = {0.f, 0.f, 0.f, 0.f};
#pragma unroll
    for (int ct = 0; ct < 4; ++ct) {          // 4 col-tiles of 16
        f4 acc = {0.f, 0.f, 0.f, 0.f};
#pragma unroll
        for (int kb = 0; kb < 4; ++kb) {
            const bf16x8 b = *(const bf16x8*)&wls[(ct * 16 + m) * WS_STRIDE + kb * 32 + kq * 8];
            acc = __builtin_amdgcn_mfma_f32_16x16x32_bf16(afr[kb], b, acc, 0, 0, 0);
        }
        const float a1 = attn[ct * 16 + m];
        const float a2 = attn[64 + ct * 16 + m];
#pragma unroll
        for (int r = 0; r < 4; ++r) {
            sacc[r] = fmaf(acc[r], a1, sacc[r]);
            tacc[r] = fmaf(acc[r], a2, tacc[r]);
            const int row = base + w * 16 + kq * 4 + r;   // C: row=(lane>>4)*4+reg
            if (row < N_NODES)
                hbuf[row * OUT_CH + ct * 16 + m] = (unsigned short)f2b(acc[r]);
        }
    }
    // reduce s/t over the 16 col-lanes (lane bits 0..3)
#pragma unroll
    for (int off = 1; off < 16; off <<= 1) {
#pragma unroll
        for (int r = 0; r < 4; ++r) {
            sacc[r] += __shfl_xor(sacc[r], off, 64);
            tacc[r] += __shfl_xor(tacc[r], off, 64);
        }
    }
    if (m == 0) {
#pragma unroll
        for (int r = 0; r < 4; ++r) {
            const int row = base + w * 16 + kq * 4 + r;
            if (row < N_NODES) { s[row] = sacc[r]; t[row] = tacc[r]; }
        }
    }
}

// Fused weight+gather. The weight_pass->gather_out kernel boundary existed
// only to make Z global; replace it with a grid-wide sync and keep the
// buckets in LDS — no cv/count global roundtrip, one fewer launch.
//
// R8 change: the hand-rolled arrive-and-spin barrier is replaced by
// cooperative-groups grid sync (hipLaunchCooperativeKernel). The runtime
// VALIDATES co-residency at launch and returns an error instead of
// deadlocking — the suspected cause of R8's container failure.
//
// Phase 1 (== old weight_pass): block owns all edges with dst in
// [bin*256, bin*256+256); ranks via LDS atomics, buckets in 64KB LDS,
// Z contribution via one device-scope atomicAdd.
// Phase 2 (== old gather_out, bkt read from LDS): wave wv handles the
// 16 dsts wv*16..wv*16+15; slot = lane>>3 (8 edge slots), q = lane&7
// (16B chunk of the 128B bf16 h row); uint4 h loads, xor-reduce over
// slot bits, slot doubles as head index for 2 coalesced nontemporal
// float4 stores covering all 8 head copies.
__global__ __launch_bounds__(1024) void weight_gather(
        const unsigned* __restrict__ binned,
        const int* __restrict__ bin_count,
        const float* __restrict__ s,
        const float* __restrict__ t,
        const unsigned short* __restrict__ hbuf,
        float* __restrict__ Zsum,
        float* __restrict__ out) {
    __shared__ unsigned bkt[256 * MAXDEG];   // 64 KB
    __shared__ unsigned cnt_l[256];
    __shared__ float s_l[256];
    __shared__ float red[16];
    __shared__ float zsh;
    const int tid = threadIdx.x;
    const int bin = blockIdx.x;
    if (tid < 256) {
        cnt_l[tid] = 0u;
        const int d = bin * 256 + tid;
        s_l[tid] = (d < N_NODES) ? s[d] : 0.0f;
    }
    __syncthreads();
    int n = bin_count[bin];
    if (n > BINCAP) n = BINCAP;
    float zs = 0.0f;
    for (int i = tid; i < n; i += 1024) {
        const unsigned e = binned[bin * BINCAP + i];
        const int dl = (int)((e >> 16) & 255u);
        const int src = (int)(e & 0xFFFFu);
        const float w = __expf(lrelu(s_l[dl] + t[src]));
        zs += w;
        const unsigned r = atomicAdd(&cnt_l[dl], 1u);
        if (r < MAXDEG) bkt[dl * MAXDEG + r] = (f2b(w) << 16) | (unsigned)src;
    }
    // block Z partial -> one global atomic, then grid-wide sync
#pragma unroll
    for (int off = 32; off > 0; off >>= 1)
        zs += __shfl_down(zs, off, 64);
    if ((tid & 63) == 0) red[tid >> 6] = zs;
    __syncthreads();
    if (tid == 0) {
        float v = 0.0f;
#pragma unroll
        for (int k = 0; k < 16; ++k) v += red[k];
        atomicAdd(Zsum, v);
    }
    __threadfence();
    cg::this_grid().sync();
    if (tid == 0) zsh = 1.0f / *(volatile float*)Zsum;
    __syncthreads();
    const float z = zsh;
    // ---------------- phase 2: gather + output ----------------
    const int wv = tid >> 6, lane = tid & 63;
    const int slot = lane >> 3;          // edge slot 0..7
    const int q = lane & 7;              // 16B chunk 0..7 of the h row
    const uint4* h4 = (const uint4*)hbuf;
    f4* out4 = (f4*)out;
    for (int k = 0; k < 16; ++k) {
        const int dl = wv * 16 + k;
        const int node = bin * 256 + dl;
        if (node >= N_NODES) break;      // only bin 195 tail
        int cnt = (int)cnt_l[dl];
        cnt = cnt < MAXDEG ? cnt : MAXDEG;   // match drop semantics
        f4 a0 = (f4)(0.0f);
        f4 a1 = (f4)(0.0f);
        for (int i = 0; i < cnt; i += 8) {
            const int ee = i + slot;
            unsigned pk = 0u;                // src=0, weight=+0.0f for idle slots
            if (ee < cnt) pk = bkt[dl * MAXDEG + ee];
            const int c = (int)(pk & 0xFFFFu);
            const float w = __uint_as_float(pk & 0xFFFF0000u);   // bf16 weight
            const uint4 hv = h4[c * 8 + q];                      // 8 bf16 h values
            a0.x = fmaf(w, __uint_as_float(hv.x << 16),        a0.x);
            a0.y = fmaf(w, __uint_as_float(hv.x & 0xFFFF0000u), a0.y);
            a0.z = fmaf(w, __uint_as_float(hv.y << 16),        a0.z);
            a0.w = fmaf(w, __uint_as_float(hv.y & 0xFFFF0000u), a0.w);
            a1.x = fmaf(w, __uint_as_float(hv.z << 16),        a1.x);
            a1.y = fmaf(w, __uint_as_float(hv.z & 0xFFFF0000u), a1.y);
            a1.z = fmaf(w, __uint_as_float(hv.w << 16),        a1.z);
            a1.w = fmaf(w, __uint_as_float(hv.w & 0xFFFF0000u), a1.w);
        }
        // reduce across the 8 slots (lane bits 3,4,5)
#pragma unroll
        for (int off = 8; off <= 32; off <<= 1) {
            a0.x += __shfl_xor(a0.x, off, 64);
            a0.y += __shfl_xor(a0.y, off, 64);
            a0.z += __shfl_xor(a0.z, off, 64);
            a0.w += __shfl_xor(a0.w, off, 64);
            a1.x += __shfl_xor(a1.x, off, 64);
            a1.y += __shfl_xor(a1.y, off, 64);
            a1.z += __shfl_xor(a1.z, off, 64);
            a1.w += __shfl_xor(a1.w, off, 64);
        }
        a0 *= z;
        a1 *= z;
        // head = slot: float4 idx slot*16 + q*2 within the 128-float4 row
        const int ob = node * 128 + slot * 16 + q * 2;
        __builtin_nontemporal_store(a0, out4 + ob);
        __builtin_nontemporal_store(a1, out4 + ob + 1);
    }
}

extern "C" void kernel_launch(void* const* d_in, const int* in_sizes, int n_in,
                              void* d_out, int out_size, void* d_ws, size_t ws_size,
                              hipStream_t stream) {
    const float* x    = (const float*)d_in[0];
    const int*   eidx = (const int*)d_in[1];
    const float* W    = (const float*)d_in[2];
    const float* attn = (const float*)d_in[3];
    float* out = (float*)d_out;

    unsigned short* hbuf = (unsigned short*)d_ws;           // 3,200,000 bf16 (6.4 MB)
    float* s        = (float*)(hbuf + N_NODES * OUT_CH);    // 50,000
    float* t        = s + N_NODES;                          // 50,000
    int* bin_count  = (int*)(t + N_NODES);                  // 196
    float* Zsum     = (float*)(bin_count + NBIN);           // 1
    unsigned* binned= (unsigned*)(Zsum + 1);                // 196*4608 u32 (3.6 MB)

    const int4* ei4 = (const int4*)eidx;              // destinations
    const int4* ej4 = (const int4*)(eidx + N_EDGES);  // sources

    hipMemsetAsync(bin_count, 0, (NBIN + 1) * sizeof(int), stream);  // bin_count + Zsum
    gemm_bin<<<NBLK_G + NBLK_A, 256, 0, stream>>>(x, W, attn, ei4, ej4,
                                                  hbuf, s, t, bin_count, binned);
    {
        const unsigned* a_binned   = binned;
        const int*      a_bincnt   = bin_count;
        const float*    a_s        = s;
        const float*    a_t        = t;
        const unsigned short* a_h  = hbuf;
        float*          a_Z        = Zsum;
        float*          a_out      = out;
        void* args[] = {(void*)&a_binned, (void*)&a_bincnt, (void*)&a_s,
                        (void*)&a_t, (void*)&a_h, (void*)&a_Z, (void*)&a_out};
        hipLaunchCooperativeKernel((const void*)weight_gather, dim3(NBIN),
                                   dim3(1024), args, 0, stream);
    }
}

// Round 10
// 178.331 us; speedup vs baseline: 1.5019x; 1.5019x over previous
//
#include <hip/hip_runtime.h>

#define N_NODES 50000
#define N_EDGES 800000
#define IN_CH 128
#define OUT_CH 64
#define HEADS 8
#define ROW 512           // OUT_CH*HEADS, floats per output row
#define NBLK_G 782        // ceil(N_NODES / 64) gemm tiles
#define NBLK_A 782        // ceil(N_EDGES/4 / 256) bin blocks (200000 int4-groups)
#define NCELL NBLK_A      // one cell per bin-block
#define NBIN 196          // dst>>8 bins (dst<50000 -> bin 0..195), 256 dsts/bin
#define CAP2 32           // per-(bin,block) cell capacity; Poisson(5.2) tail P(>=33) ~ 1e-17
#define MAXDEG 64         // padded bucket; P(deg>=64) ~ 1e-13 for B(800k,1/50k)
#define WS_STRIDE 136     // shorts per LDS row: 128 + 8 pad (272B, 16B-aligned)

typedef float f4 __attribute__((ext_vector_type(4)));
typedef short bf16x8 __attribute__((ext_vector_type(8)));

__device__ __forceinline__ float lrelu(float z) {
    return z > 0.0f ? z : 0.2f * z;
}

// fp32 -> bf16 (RNE) as raw 16-bit
__device__ __forceinline__ unsigned f2b(float f) {
    unsigned u = __float_as_uint(f);
    return (u + 0x7FFFu + ((u >> 16) & 1u)) >> 16;
}

// Fused kernel, parity-interleaved roles (R5: gemm and binning are
// independent; even blocks do a gemm tile, odd blocks a bin block).
//
// R10 bin role: FIXED per-(bin,block) cells — binned[bin][cell][CAP2].
// Rank comes from an LDS cur[] atomic only; the placement address is
// fully determined by (bin, cell, rank). This deletes the 800k LDS
// histogram atomics, the 153k device-scope bin_count atomicAdds (780
// serialized RMWs per word whose RETURN blocked placement), and one
// barrier phase. Per-cell counts -> plain stores to cellcnt[bin][cell].
__global__ __launch_bounds__(256) void gemm_bin(const float* __restrict__ x,
                                                const float* __restrict__ W,
                                                const float* __restrict__ attn,
                                                const int4* __restrict__ ei4,
                                                const int4* __restrict__ ej4,
                                                unsigned short* __restrict__ hbuf,
                                                float* __restrict__ s,
                                                float* __restrict__ t,
                                                unsigned* __restrict__ cellcnt,
                                                unsigned* __restrict__ binned) {
    __shared__ unsigned short xs[64 * WS_STRIDE];   // 17.4 KB, x tile in bf16
    __shared__ unsigned short wls[64 * WS_STRIDE];  // 17.4 KB, W^T in bf16
    const int tid = threadIdx.x;
    const int bid = blockIdx.x;

    if (bid & 1) {
        // ---------------- bin role (odd blocks) ----------------
        unsigned* cur = (unsigned*)xs;       // overlay: 196*4B
        if (tid < NBIN) cur[tid] = 0u;
        __syncthreads();
        const int cell = bid >> 1;
        const int g = cell * 256 + tid;      // int4-group id
        if (g < N_EDGES / 4) {
            const int4 li = ei4[g];
            const int4 lj = ej4[g];
            const int b0 = li.x >> 8, b1 = li.y >> 8, b2 = li.z >> 8, b3 = li.w >> 8;
            const unsigned p0 = atomicAdd(&cur[b0], 1u);
            if (p0 < CAP2) binned[(unsigned)(b0 * NCELL + cell) * CAP2 + p0] =
                ((unsigned)(li.x & 255) << 16) | (unsigned)lj.x;
            const unsigned p1 = atomicAdd(&cur[b1], 1u);
            if (p1 < CAP2) binned[(unsigned)(b1 * NCELL + cell) * CAP2 + p1] =
                ((unsigned)(li.y & 255) << 16) | (unsigned)lj.y;
            const unsigned p2 = atomicAdd(&cur[b2], 1u);
            if (p2 < CAP2) binned[(unsigned)(b2 * NCELL + cell) * CAP2 + p2] =
                ((unsigned)(li.z & 255) << 16) | (unsigned)lj.z;
            const unsigned p3 = atomicAdd(&cur[b3], 1u);
            if (p3 < CAP2) binned[(unsigned)(b3 * NCELL + cell) * CAP2 + p3] =
                ((unsigned)(li.w & 255) << 16) | (unsigned)lj.w;
        }
        __syncthreads();
        if (tid < NBIN) {
            const unsigned c = cur[tid];
            cellcnt[(unsigned)tid * NCELL + cell] = c < CAP2 ? c : CAP2;
        }
        return;
    }

    // ---------------- gemm role (even blocks) ----------------
    const int base = (bid >> 1) * 64;
    {   // stage W transposed -> bf16: wls[col][k]
        const float4* W4 = (const float4*)W;
#pragma unroll
        for (int j = 0; j < 8; ++j) {
            const int idx = tid + j * 256;   // float4 index into [128][16]
            const int k = idx >> 4;
            const int c = (idx & 15) * 4;
            const float4 v = W4[idx];
            wls[(c + 0) * WS_STRIDE + k] = (unsigned short)f2b(v.x);
            wls[(c + 1) * WS_STRIDE + k] = (unsigned short)f2b(v.y);
            wls[(c + 2) * WS_STRIDE + k] = (unsigned short)f2b(v.z);
            wls[(c + 3) * WS_STRIDE + k] = (unsigned short)f2b(v.w);
        }
    }
    {   // stage x tile as bf16 (RNE at staging — same values as before)
        const float4* x4 = (const float4*)x;
#pragma unroll
        for (int j = 0; j < 8; ++j) {
            const int idx = tid + j * 256;   // float4 index into [64][32]
            const int r = idx >> 5;
            const int kq = idx & 31;
            const int row = base + r;
            float4 v = make_float4(0.f, 0.f, 0.f, 0.f);
            if (row < N_NODES) v = x4[row * 32 + kq];
            ushort4 pb;
            pb.x = (unsigned short)f2b(v.x);
            pb.y = (unsigned short)f2b(v.y);
            pb.z = (unsigned short)f2b(v.z);
            pb.w = (unsigned short)f2b(v.w);
            *(ushort4*)&xs[r * WS_STRIDE + kq * 4] = pb;
        }
    }
    __syncthreads();
    const int w = tid >> 6, lane = tid & 63;
    const int m = lane & 15;       // A row / B-C col within tile
    const int kq = lane >> 4;      // k-chunk quad / C row-quad
    bf16x8 afr[4];
#pragma unroll
    for (int kb = 0; kb < 4; ++kb)
        afr[kb] = *(const bf16x8*)&xs[(w * 16 + m) * WS_STRIDE + kb * 32 + kq * 8];
    float sacc[4] = {0.f, 0.f, 0.f, 0.f};
    float tacc[4] = {0.f, 0.f, 0.f, 0.f};
#pragma unroll
    for (int ct = 0; ct < 4; ++ct) {          // 4 col-tiles of 16
        f4 acc = {0.f, 0.f, 0.f, 0.f};
#pragma unroll
        for (int kb = 0; kb < 4; ++kb) {
            const bf16x8 b = *(const bf16x8*)&wls[(ct * 16 + m) * WS_STRIDE + kb * 32 + kq * 8];
            acc = __builtin_amdgcn_mfma_f32_16x16x32_bf16(afr[kb], b, acc, 0, 0, 0);
        }
        const float a1 = attn[ct * 16 + m];
        const float a2 = attn[64 + ct * 16 + m];
#pragma unroll
        for (int r = 0; r < 4; ++r) {
            sacc[r] = fmaf(acc[r], a1, sacc[r]);
            tacc[r] = fmaf(acc[r], a2, tacc[r]);
            const int row = base + w * 16 + kq * 4 + r;   // C: row=(lane>>4)*4+reg
            if (row < N_NODES)
                hbuf[row * OUT_CH + ct * 16 + m] = (unsigned short)f2b(acc[r]);
        }
    }
    // reduce s/t over the 16 col-lanes (lane bits 0..3)
#pragma unroll
    for (int off = 1; off < 16; off <<= 1) {
#pragma unroll
        for (int r = 0; r < 4; ++r) {
            sacc[r] += __shfl_xor(sacc[r], off, 64);
            tacc[r] += __shfl_xor(tacc[r], off, 64);
        }
    }
    if (m == 0) {
#pragma unroll
        for (int r = 0; r < 4; ++r) {
            const int row = base + w * 16 + kq * 4 + r;
            if (row < N_NODES) { s[row] = sacc[r]; t[row] = tacc[r]; }
        }
    }
}

// One block per bin (R6 structure, R10 read side): thread c owns cell c
// (782 active of 1024); reads its cell's count (coalesced) and up to
// CAP2 packed edges via uint4 loads, computes w = exp(lrelu(s+t)),
// ranks via LDS atomics into the 64KB bkt, then flushes cv + count
// fully coalesced. Z contribution: one device-scope atomicAdd per block.
__global__ __launch_bounds__(1024) void weight_pass(const unsigned* __restrict__ binned,
                                                    const unsigned* __restrict__ cellcnt,
                                                    const float* __restrict__ s,
                                                    const float* __restrict__ t,
                                                    unsigned* __restrict__ cv,
                                                    int* __restrict__ count,
                                                    float* __restrict__ Zsum) {
    __shared__ unsigned bkt[256 * MAXDEG];   // 64 KB
    __shared__ unsigned cnt_l[256];
    __shared__ float s_l[256];
    __shared__ float red[16];
    const int tid = threadIdx.x;
    const int bin = blockIdx.x;
    if (tid < 256) {
        cnt_l[tid] = 0u;
        const int d = bin * 256 + tid;
        s_l[tid] = (d < N_NODES) ? s[d] : 0.0f;
    }
    __syncthreads();
    float zs = 0.0f;
#define PROC(eu) do { \
        const unsigned e = (eu); \
        const int dl = (int)((e >> 16) & 255u); \
        const int src = (int)(e & 0xFFFFu); \
        const float wv_ = __expf(lrelu(s_l[dl] + t[src])); \
        zs += wv_; \
        const unsigned r_ = atomicAdd(&cnt_l[dl], 1u); \
        if (r_ < MAXDEG) bkt[dl * MAXDEG + r_] = (f2b(wv_) << 16) | (unsigned)src; \
    } while (0)
    for (int c = tid; c < NCELL; c += 1024) {        // one trip (782 < 1024)
        const int cnt = (int)cellcnt[(unsigned)bin * NCELL + c];
        const uint4* cp4 = (const uint4*)&binned[(unsigned)(bin * NCELL + c) * CAP2];
        for (int k4 = 0; k4 * 4 < cnt; ++k4) {
            const uint4 e4 = cp4[k4];
            const int kb = k4 * 4;
            PROC(e4.x);
            if (kb + 1 < cnt) PROC(e4.y);
            if (kb + 2 < cnt) PROC(e4.z);
            if (kb + 3 < cnt) PROC(e4.w);
        }
    }
#undef PROC
    __syncthreads();
    {   // coalesced cv flush: 16384 u32 = 4096 uint4 (slots >= cnt are garbage,
        // never read by gather_out)
        uint4* cv4 = (uint4*)(cv + bin * (256 * MAXDEG));
        const uint4* b4 = (const uint4*)bkt;
        for (int i = tid; i < 4096; i += 1024) cv4[i] = b4[i];
    }
    if (tid < 256) {
        const int d = bin * 256 + tid;
        if (d < N_NODES) count[d] = (int)cnt_l[tid];
    }
    // block Z partial -> one global atomic
#pragma unroll
    for (int off = 32; off > 0; off >>= 1)
        zs += __shfl_down(zs, off, 64);
    if ((tid & 63) == 0) red[tid >> 6] = zs;
    __syncthreads();
    if (tid == 0) {
        float v = 0.0f;
#pragma unroll
        for (int k = 0; k < 16; ++k) v += red[k];
        atomicAdd(Zsum, v);
    }
}

// one wave per destination node; slot = lane>>3 (8 edge slots), q = lane&7
// (16-byte chunk of the 128-byte bf16 h row). One uint4 load = 8 h values,
// 8 edges per wave-trip; cv for the next trip is prefetched so its latency
// hides under the h-load + FMA of the current trip. After the xor-reduce
// over slot bits every slot holds the full row sum, so slot doubles as the
// head index: 2 nontemporal float4 stores/lane cover all 8 head copies.
__global__ __launch_bounds__(256) void gather_out(const int* __restrict__ count,
                                                  const unsigned* __restrict__ cv,
                                                  const float* __restrict__ Zsum,
                                                  const unsigned short* __restrict__ hbuf,
                                                  float* __restrict__ out) {
    const int n = blockIdx.x * 4 + (threadIdx.x >> 6);  // 12500*4 = 50000 exact
    const int lane = threadIdx.x & 63;
    const int slot = lane >> 3;          // edge slot 0..7
    const int q = lane & 7;              // 16B chunk 0..7 of the h row
    const float z = 1.0f / Zsum[0];
    int cnt = count[n];
    cnt = cnt < MAXDEG ? cnt : MAXDEG;   // match weight_pass drop semantics
    const int base = n * MAXDEG;
    const uint4* h4 = (const uint4*)hbuf;
    f4 a0 = (f4)(0.0f);
    f4 a1 = (f4)(0.0f);
    unsigned pk = 0u;                    // src=0, weight=+0.0f for idle slots
    if (slot < cnt) pk = cv[base + slot];
    for (int i = 0; i < cnt; i += 8) {
        const int c = (int)(pk & 0xFFFFu);
        const float w = __uint_as_float(pk & 0xFFFF0000u);   // bf16 weight
        unsigned pk_n = 0u;
        const int ee = i + 8 + slot;
        if (ee < cnt) pk_n = cv[base + ee];                  // prefetch next trip
        const uint4 hv = h4[c * 8 + q];                      // 8 bf16 h values
        a0.x = fmaf(w, __uint_as_float(hv.x << 16),        a0.x);
        a0.y = fmaf(w, __uint_as_float(hv.x & 0xFFFF0000u), a0.y);
        a0.z = fmaf(w, __uint_as_float(hv.y << 16),        a0.z);
        a0.w = fmaf(w, __uint_as_float(hv.y & 0xFFFF0000u), a0.w);
        a1.x = fmaf(w, __uint_as_float(hv.z << 16),        a1.x);
        a1.y = fmaf(w, __uint_as_float(hv.z & 0xFFFF0000u), a1.y);
        a1.z = fmaf(w, __uint_as_float(hv.w << 16),        a1.z);
        a1.w = fmaf(w, __uint_as_float(hv.w & 0xFFFF0000u), a1.w);
        pk = pk_n;
    }
    // reduce across the 8 slots (lane bits 3,4,5); every slot ends with full sum
#pragma unroll
    for (int off = 8; off <= 32; off <<= 1) {
        a0.x += __shfl_xor(a0.x, off, 64);
        a0.y += __shfl_xor(a0.y, off, 64);
        a0.z += __shfl_xor(a0.z, off, 64);
        a0.w += __shfl_xor(a0.w, off, 64);
        a1.x += __shfl_xor(a1.x, off, 64);
        a1.y += __shfl_xor(a1.y, off, 64);
        a1.z += __shfl_xor(a1.z, off, 64);
        a1.w += __shfl_xor(a1.w, off, 64);
    }
    a0 *= z;
    a1 *= z;
    f4* out4 = (f4*)out;
    // head = slot: float4 idx slot*16 + q*2 within the 128-float4 row
    const int ob = n * 128 + slot * 16 + q * 2;
    __builtin_nontemporal_store(a0, out4 + ob);
    __builtin_nontemporal_store(a1, out4 + ob + 1);
}

extern "C" void kernel_launch(void* const* d_in, const int* in_sizes, int n_in,
                              void* d_out, int out_size, void* d_ws, size_t ws_size,
                              hipStream_t stream) {
    const float* x    = (const float*)d_in[0];
    const int*   eidx = (const int*)d_in[1];
    const float* W    = (const float*)d_in[2];
    const float* attn = (const float*)d_in[3];
    float* out = (float*)d_out;

    unsigned short* hbuf = (unsigned short*)d_ws;            // 3,200,000 bf16 (6.4 MB)
    unsigned* binned = (unsigned*)(hbuf + N_NODES * OUT_CH); // 196*782*32 u32 (19.6 MB, 128B-aligned)
    unsigned* cv     = binned + NBIN * NCELL * CAP2;         // 196*16384 u32 (12.85 MB)
    float* s         = (float*)(cv + NBIN * 256 * MAXDEG);   // 50,000
    float* t         = s + N_NODES;                          // 50,000
    int* count       = (int*)(t + N_NODES);                  // 50,000
    unsigned* cellcnt= (unsigned*)(count + N_NODES);         // 196*782 u32 (613 KB)
    float* Zsum      = (float*)(cellcnt + NBIN * NCELL);     // 1

    const int4* ei4 = (const int4*)eidx;              // destinations
    const int4* ej4 = (const int4*)(eidx + N_EDGES);  // sources

    hipMemsetAsync(Zsum, 0, sizeof(float), stream);
    gemm_bin   <<<NBLK_G + NBLK_A, 256, 0, stream>>>(x, W, attn, ei4, ej4,
                                                     hbuf, s, t, cellcnt, binned);
    weight_pass<<<NBIN, 1024, 0, stream>>>(binned, cellcnt, s, t, cv, count, Zsum);
    gather_out <<<N_NODES / 4, 256, 0, stream>>>(count, cv, Zsum, hbuf, out);
}

// Round 11
// 177.194 us; speedup vs baseline: 1.5115x; 1.0064x over previous
//
#include <hip/hip_runtime.h>

#define N_NODES 50000
#define N_EDGES 800000
#define IN_CH 128
#define OUT_CH 64
#define HEADS 8
#define ROW 512           // OUT_CH*HEADS, floats per output row
#define NBLK_G 782        // ceil(N_NODES / 64) gemm tiles
#define NBLK_A 782        // ceil(N_EDGES/4 / 256) bin blocks (200000 int4-groups)
#define NBIN 392          // dst>>7 bins (dst<50000 -> bin 0..390), 128 dsts/bin
#define BINW 128          // dsts per bin
#define BINCAP 2336       // per-bin edge capacity; Binom mean 2041, sd 45, 6.5-sigma pad
#define MAXDEG 64         // padded bucket; P(deg>=64) ~ 1e-13 for B(800k,1/50k)
#define WS_STRIDE 136     // shorts per LDS row: 128 + 8 pad (272B, 16B-aligned)

typedef float f4 __attribute__((ext_vector_type(4)));
typedef short bf16x8 __attribute__((ext_vector_type(8)));

__device__ __forceinline__ float lrelu(float z) {
    return z > 0.0f ? z : 0.2f * z;
}

// fp32 -> bf16 (RNE) as raw 16-bit
__device__ __forceinline__ unsigned f2b(float f) {
    unsigned u = __float_as_uint(f);
    return (u + 0x7FFFu + ((u >> 16) & 1u)) >> 16;
}

// Fused kernel, parity-interleaved roles (R5/R6 confirmed: gemm and
// binning are independent; even blocks do a gemm tile, odd blocks a bin
// block, so every CU co-hosts compute-heavy and latency-bound waves).
//
// R11: bins are 128-dst wide (dst>>7, 392 bins) so that weight_pass gets
// a 392-block grid (full CU coverage — the 196-block version left 23% of
// CUs idle). Bin role otherwise identical to R6 (LDS histogram + one
// global reserve atomic per touched bin + contiguous chunk placement).
__global__ __launch_bounds__(256) void gemm_bin(const float* __restrict__ x,
                                                const float* __restrict__ W,
                                                const float* __restrict__ attn,
                                                const int4* __restrict__ ei4,
                                                const int4* __restrict__ ej4,
                                                unsigned short* __restrict__ hbuf,
                                                float* __restrict__ s,
                                                float* __restrict__ t,
                                                int* __restrict__ bin_count,
                                                unsigned* __restrict__ binned) {
    __shared__ unsigned short xs[64 * WS_STRIDE];   // 17.4 KB, x tile in bf16
    __shared__ unsigned short wls[64 * WS_STRIDE];  // 17.4 KB, W^T in bf16
    const int tid = threadIdx.x;
    const int bid = blockIdx.x;

    if (bid & 1) {
        // ---------------- bin role (odd blocks) ----------------
        unsigned* hist = (unsigned*)xs;      // overlay: 3*392*4B = 4.7 KB
        unsigned* bse  = hist + NBIN;
        unsigned* cur  = bse + NBIN;
        for (int i = tid; i < NBIN; i += 256) { hist[i] = 0u; cur[i] = 0u; }
        __syncthreads();
        const int g = (bid >> 1) * 256 + tid;   // int4-group id
        const bool act = g < N_EDGES / 4;
        int4 li = make_int4(0, 0, 0, 0), lj = make_int4(0, 0, 0, 0);
        if (act) {
            li = ei4[g];
            lj = ej4[g];
            atomicAdd(&hist[li.x >> 7], 1u);
            atomicAdd(&hist[li.y >> 7], 1u);
            atomicAdd(&hist[li.z >> 7], 1u);
            atomicAdd(&hist[li.w >> 7], 1u);
        }
        __syncthreads();
        for (int i = tid; i < NBIN; i += 256) {
            const unsigned c = hist[i];
            bse[i] = c ? (unsigned)atomicAdd(&bin_count[i], (int)c) : 0u;
        }
        __syncthreads();
        if (act) {
            const unsigned p0 = bse[li.x >> 7] + atomicAdd(&cur[li.x >> 7], 1u);
            if (p0 < BINCAP) binned[(li.x >> 7) * BINCAP + p0] =
                ((unsigned)(li.x & 127) << 16) | (unsigned)lj.x;
            const unsigned p1 = bse[li.y >> 7] + atomicAdd(&cur[li.y >> 7], 1u);
            if (p1 < BINCAP) binned[(li.y >> 7) * BINCAP + p1] =
                ((unsigned)(li.y & 127) << 16) | (unsigned)lj.y;
            const unsigned p2 = bse[li.z >> 7] + atomicAdd(&cur[li.z >> 7], 1u);
            if (p2 < BINCAP) binned[(li.z >> 7) * BINCAP + p2] =
                ((unsigned)(li.z & 127) << 16) | (unsigned)lj.z;
            const unsigned p3 = bse[li.w >> 7] + atomicAdd(&cur[li.w >> 7], 1u);
            if (p3 < BINCAP) binned[(li.w >> 7) * BINCAP + p3] =
                ((unsigned)(li.w & 127) << 16) | (unsigned)lj.w;
        }
        return;
    }

    // ---------------- gemm role (even blocks) ----------------
    const int base = (bid >> 1) * 64;
    {   // stage W transposed -> bf16: wls[col][k]
        const float4* W4 = (const float4*)W;
#pragma unroll
        for (int j = 0; j < 8; ++j) {
            const int idx = tid + j * 256;   // float4 index into [128][16]
            const int k = idx >> 4;
            const int c = (idx & 15) * 4;
            const float4 v = W4[idx];
            wls[(c + 0) * WS_STRIDE + k] = (unsigned short)f2b(v.x);
            wls[(c + 1) * WS_STRIDE + k] = (unsigned short)f2b(v.y);
            wls[(c + 2) * WS_STRIDE + k] = (unsigned short)f2b(v.z);
            wls[(c + 3) * WS_STRIDE + k] = (unsigned short)f2b(v.w);
        }
    }
    {   // stage x tile as bf16 (RNE at staging — same values as before)
        const float4* x4 = (const float4*)x;
#pragma unroll
        for (int j = 0; j < 8; ++j) {
            const int idx = tid + j * 256;   // float4 index into [64][32]
            const int r = idx >> 5;
            const int kq = idx & 31;
            const int row = base + r;
            float4 v = make_float4(0.f, 0.f, 0.f, 0.f);
            if (row < N_NODES) v = x4[row * 32 + kq];
            ushort4 pb;
            pb.x = (unsigned short)f2b(v.x);
            pb.y = (unsigned short)f2b(v.y);
            pb.z = (unsigned short)f2b(v.z);
            pb.w = (unsigned short)f2b(v.w);
            *(ushort4*)&xs[r * WS_STRIDE + kq * 4] = pb;
        }
    }
    __syncthreads();
    const int w = tid >> 6, lane = tid & 63;
    const int m = lane & 15;       // A row / B-C col within tile
    const int kq = lane >> 4;      // k-chunk quad / C row-quad
    bf16x8 afr[4];
#pragma unroll
    for (int kb = 0; kb < 4; ++kb)
        afr[kb] = *(const bf16x8*)&xs[(w * 16 + m) * WS_STRIDE + kb * 32 + kq * 8];
    float sacc[4] = {0.f, 0.f, 0.f, 0.f};
    float tacc[4] = {0.f, 0.f, 0.f, 0.f};
#pragma unroll
    for (int ct = 0; ct < 4; ++ct) {          // 4 col-tiles of 16
        f4 acc = {0.f, 0.f, 0.f, 0.f};
#pragma unroll
        for (int kb = 0; kb < 4; ++kb) {
            const bf16x8 b = *(const bf16x8*)&wls[(ct * 16 + m) * WS_STRIDE + kb * 32 + kq * 8];
            acc = __builtin_amdgcn_mfma_f32_16x16x32_bf16(afr[kb], b, acc, 0, 0, 0);
        }
        const float a1 = attn[ct * 16 + m];
        const float a2 = attn[64 + ct * 16 + m];
#pragma unroll
        for (int r = 0; r < 4; ++r) {
            sacc[r] = fmaf(acc[r], a1, sacc[r]);
            tacc[r] = fmaf(acc[r], a2, tacc[r]);
            const int row = base + w * 16 + kq * 4 + r;   // C: row=(lane>>4)*4+reg
            if (row < N_NODES)
                hbuf[row * OUT_CH + ct * 16 + m] = (unsigned short)f2b(acc[r]);
        }
    }
    // reduce s/t over the 16 col-lanes (lane bits 0..3)
#pragma unroll
    for (int off = 1; off < 16; off <<= 1) {
#pragma unroll
        for (int r = 0; r < 4; ++r) {
            sacc[r] += __shfl_xor(sacc[r], off, 64);
            tacc[r] += __shfl_xor(tacc[r], off, 64);
        }
    }
    if (m == 0) {
#pragma unroll
        for (int r = 0; r < 4; ++r) {
            const int row = base + w * 16 + kq * 4 + r;
            if (row < N_NODES) { s[row] = sacc[r]; t[row] = tacc[r]; }
        }
    }
}

// One block per 128-dst bin (392 blocks — full CU coverage, vs 196 at
// 256-dst which idled 23% of CUs): ranks via LDS atomics (zero global
// atomics), buckets in 32KB LDS, cv + count written fully COALESCED.
// s[] for the dst range LDS-staged; only scattered op is the t[src]
// gather (L2-resident). Z: one device-scope atomicAdd per block.
__global__ __launch_bounds__(1024) void weight_pass(const unsigned* __restrict__ binned,
                                                    const int* __restrict__ bin_count,
                                                    const float* __restrict__ s,
                                                    const float* __restrict__ t,
                                                    unsigned* __restrict__ cv,
                                                    int* __restrict__ count,
                                                    float* __restrict__ Zsum) {
    __shared__ unsigned bkt[BINW * MAXDEG];  // 32 KB
    __shared__ unsigned cnt_l[BINW];
    __shared__ float s_l[BINW];
    __shared__ float red[16];
    const int tid = threadIdx.x;
    const int bin = blockIdx.x;
    if (tid < BINW) {
        cnt_l[tid] = 0u;
        const int d = bin * BINW + tid;
        s_l[tid] = (d < N_NODES) ? s[d] : 0.0f;
    }
    __syncthreads();
    int n = bin_count[bin];
    if (n > BINCAP) n = BINCAP;
    float zs = 0.0f;
    for (int i = tid; i < n; i += 1024) {
        const unsigned e = binned[bin * BINCAP + i];
        const int dl = (int)((e >> 16) & 127u);
        const int src = (int)(e & 0xFFFFu);
        const float w = __expf(lrelu(s_l[dl] + t[src]));
        zs += w;
        const unsigned r = atomicAdd(&cnt_l[dl], 1u);
        if (r < MAXDEG) bkt[dl * MAXDEG + r] = (f2b(w) << 16) | (unsigned)src;
    }
    __syncthreads();
    {   // coalesced cv flush: 8192 u32 = 2048 uint4 (slots >= cnt are garbage,
        // never read by gather_out)
        uint4* cv4 = (uint4*)(cv + bin * (BINW * MAXDEG));
        const uint4* b4 = (const uint4*)bkt;
        for (int i = tid; i < 2048; i += 1024) cv4[i] = b4[i];
    }
    if (tid < BINW) {
        const int d = bin * BINW + tid;
        if (d < N_NODES) count[d] = (int)cnt_l[tid];
    }
    // block Z partial -> one global atomic
#pragma unroll
    for (int off = 32; off > 0; off >>= 1)
        zs += __shfl_down(zs, off, 64);
    if ((tid & 63) == 0) red[tid >> 6] = zs;
    __syncthreads();
    if (tid == 0) {
        float v = 0.0f;
#pragma unroll
        for (int k = 0; k < 16; ++k) v += red[k];
        atomicAdd(Zsum, v);
    }
}

// one wave per destination node; slot = lane>>3 (8 edge slots), q = lane&7
// (16-byte chunk of the 128-byte bf16 h row). One uint4 load = 8 h values,
// 8 edges per wave-trip; cv for the next trip is prefetched so its latency
// hides under the h-load + FMA of the current trip. After the xor-reduce
// over slot bits every slot holds the full row sum, so slot doubles as the
// head index: 2 nontemporal float4 stores/lane cover all 8 head copies.
__global__ __launch_bounds__(256) void gather_out(const int* __restrict__ count,
                                                  const unsigned* __restrict__ cv,
                                                  const float* __restrict__ Zsum,
                                                  const unsigned short* __restrict__ hbuf,
                                                  float* __restrict__ out) {
    const int n = blockIdx.x * 4 + (threadIdx.x >> 6);  // 12500*4 = 50000 exact
    const int lane = threadIdx.x & 63;
    const int slot = lane >> 3;          // edge slot 0..7
    const int q = lane & 7;              // 16B chunk 0..7 of the h row
    const float z = 1.0f / Zsum[0];
    int cnt = count[n];
    cnt = cnt < MAXDEG ? cnt : MAXDEG;   // match weight_pass drop semantics
    const int base = n * MAXDEG;
    const uint4* h4 = (const uint4*)hbuf;
    f4 a0 = (f4)(0.0f);
    f4 a1 = (f4)(0.0f);
    unsigned pk = 0u;                    // src=0, weight=+0.0f for idle slots
    if (slot < cnt) pk = cv[base + slot];
    for (int i = 0; i < cnt; i += 8) {
        const int c = (int)(pk & 0xFFFFu);
        const float w = __uint_as_float(pk & 0xFFFF0000u);   // bf16 weight
        unsigned pk_n = 0u;
        const int ee = i + 8 + slot;
        if (ee < cnt) pk_n = cv[base + ee];                  // prefetch next trip
        const uint4 hv = h4[c * 8 + q];                      // 8 bf16 h values
        a0.x = fmaf(w, __uint_as_float(hv.x << 16),        a0.x);
        a0.y = fmaf(w, __uint_as_float(hv.x & 0xFFFF0000u), a0.y);
        a0.z = fmaf(w, __uint_as_float(hv.y << 16),        a0.z);
        a0.w = fmaf(w, __uint_as_float(hv.y & 0xFFFF0000u), a0.w);
        a1.x = fmaf(w, __uint_as_float(hv.z << 16),        a1.x);
        a1.y = fmaf(w, __uint_as_float(hv.z & 0xFFFF0000u), a1.y);
        a1.z = fmaf(w, __uint_as_float(hv.w << 16),        a1.z);
        a1.w = fmaf(w, __uint_as_float(hv.w & 0xFFFF0000u), a1.w);
        pk = pk_n;
    }
    // reduce across the 8 slots (lane bits 3,4,5); every slot ends with full sum
#pragma unroll
    for (int off = 8; off <= 32; off <<= 1) {
        a0.x += __shfl_xor(a0.x, off, 64);
        a0.y += __shfl_xor(a0.y, off, 64);
        a0.z += __shfl_xor(a0.z, off, 64);
        a0.w += __shfl_xor(a0.w, off, 64);
        a1.x += __shfl_xor(a1.x, off, 64);
        a1.y += __shfl_xor(a1.y, off, 64);
        a1.z += __shfl_xor(a1.z, off, 64);
        a1.w += __shfl_xor(a1.w, off, 64);
    }
    a0 *= z;
    a1 *= z;
    f4* out4 = (f4*)out;
    // head = slot: float4 idx slot*16 + q*2 within the 128-float4 row
    const int ob = n * 128 + slot * 16 + q * 2;
    __builtin_nontemporal_store(a0, out4 + ob);
    __builtin_nontemporal_store(a1, out4 + ob + 1);
}

extern "C" void kernel_launch(void* const* d_in, const int* in_sizes, int n_in,
                              void* d_out, int out_size, void* d_ws, size_t ws_size,
                              hipStream_t stream) {
    const float* x    = (const float*)d_in[0];
    const int*   eidx = (const int*)d_in[1];
    const float* W    = (const float*)d_in[2];
    const float* attn = (const float*)d_in[3];
    float* out = (float*)d_out;

    unsigned short* hbuf = (unsigned short*)d_ws;            // 3,200,000 bf16 (6.4 MB)
    unsigned* cv     = (unsigned*)(hbuf + N_NODES * OUT_CH); // 392*8192 u32 (12.85 MB, 16B-aligned)
    unsigned* binned = cv + NBIN * BINW * MAXDEG;            // 392*2336 u32 (3.66 MB, 16B-aligned)
    float* s         = (float*)(binned + NBIN * BINCAP);     // 50,000
    float* t         = s + N_NODES;                          // 50,000
    int* count       = (int*)(t + N_NODES);                  // 50,000
    int* bin_count   = count + N_NODES;                      // 392
    float* Zsum      = (float*)(bin_count + NBIN);           // 1

    const int4* ei4 = (const int4*)eidx;              // destinations
    const int4* ej4 = (const int4*)(eidx + N_EDGES);  // sources

    hipMemsetAsync(bin_count, 0, (NBIN + 1) * sizeof(int), stream);  // bin_count + Zsum
    gemm_bin   <<<NBLK_G + NBLK_A, 256, 0, stream>>>(x, W, attn, ei4, ej4,
                                                     hbuf, s, t, bin_count, binned);
    weight_pass<<<NBIN, 1024, 0, stream>>>(binned, bin_count, s, t, cv, count, Zsum);
    gather_out <<<N_NODES / 4, 256, 0, stream>>>(count, cv, Zsum, hbuf, out);
}

// Round 13
// 171.347 us; speedup vs baseline: 1.5631x; 1.0341x over previous
//
#include <hip/hip_runtime.h>

#define N_NODES 50000
#define N_EDGES 800000
#define IN_CH 128
#define OUT_CH 64
#define HEADS 8
#define ROW 512           // OUT_CH*HEADS, floats per output row
#define NBLK_G 782        // ceil(N_NODES / 64) gemm tiles
#define NBLK_A 782        // ceil(N_EDGES/4 / 256) bin blocks (200000 int4-groups)
#define NBIN 196          // dst>>8 bins (dst<50000 -> bin 0..195), 256 dsts/bin
#define BINCAP 4608       // per-bin edge capacity; Binom mean 4082, 6.5-sigma pad
#define MAXDEG 64         // padded bucket; P(deg>=64) ~ 1e-13 for B(800k,1/50k)
#define WS_STRIDE 136     // shorts per LDS row: 128 + 8 pad (272B, 16B-aligned)

typedef float f4 __attribute__((ext_vector_type(4)));
typedef short bf16x8 __attribute__((ext_vector_type(8)));

__device__ __forceinline__ float lrelu(float z) {
    return z > 0.0f ? z : 0.2f * z;
}

// fp32 -> bf16 (RNE) as raw 16-bit
__device__ __forceinline__ unsigned f2b(float f) {
    unsigned u = __float_as_uint(f);
    return (u + 0x7FFFu + ((u >> 16) & 1u)) >> 16;
}

// Fused kernel, parity-interleaved roles (R5/R6 confirmed: gemm and
// binning are independent; even blocks do a gemm tile, odd blocks a bin
// block, so every CU co-hosts compute-heavy and latency-bound waves).
// Exact R6 form (best measured: 173.8 us).
__global__ __launch_bounds__(256) void gemm_bin(const float* __restrict__ x,
                                                const float* __restrict__ W,
                                                const float* __restrict__ attn,
                                                const int4* __restrict__ ei4,
                                                const int4* __restrict__ ej4,
                                                unsigned short* __restrict__ hbuf,
                                                float* __restrict__ s,
                                                float* __restrict__ t,
                                                int* __restrict__ bin_count,
                                                unsigned* __restrict__ binned) {
    __shared__ unsigned short xs[64 * WS_STRIDE];   // 17.4 KB, x tile in bf16
    __shared__ unsigned short wls[64 * WS_STRIDE];  // 17.4 KB, W^T in bf16
    const int tid = threadIdx.x;
    const int bid = blockIdx.x;

    if (bid & 1) {
        // ---------------- bin role (odd blocks) ----------------
        unsigned* hist = (unsigned*)xs;      // overlay: 3*196*4B = 2.4 KB
        unsigned* bse  = hist + NBIN;
        unsigned* cur  = bse + NBIN;
        if (tid < NBIN) { hist[tid] = 0u; cur[tid] = 0u; }
        __syncthreads();
        const int g = (bid >> 1) * 256 + tid;   // int4-group id
        const bool act = g < N_EDGES / 4;
        int4 li = make_int4(0, 0, 0, 0), lj = make_int4(0, 0, 0, 0);
        if (act) {
            li = ei4[g];
            lj = ej4[g];
            atomicAdd(&hist[li.x >> 8], 1u);
            atomicAdd(&hist[li.y >> 8], 1u);
            atomicAdd(&hist[li.z >> 8], 1u);
            atomicAdd(&hist[li.w >> 8], 1u);
        }
        __syncthreads();
        if (tid < NBIN) {
            const unsigned c = hist[tid];
            bse[tid] = c ? (unsigned)atomicAdd(&bin_count[tid], (int)c) : 0u;
        }
        __syncthreads();
        if (act) {
            const unsigned p0 = bse[li.x >> 8] + atomicAdd(&cur[li.x >> 8], 1u);
            if (p0 < BINCAP) binned[(li.x >> 8) * BINCAP + p0] =
                ((unsigned)(li.x & 255) << 16) | (unsigned)lj.x;
            const unsigned p1 = bse[li.y >> 8] + atomicAdd(&cur[li.y >> 8], 1u);
            if (p1 < BINCAP) binned[(li.y >> 8) * BINCAP + p1] =
                ((unsigned)(li.y & 255) << 16) | (unsigned)lj.y;
            const unsigned p2 = bse[li.z >> 8] + atomicAdd(&cur[li.z >> 8], 1u);
            if (p2 < BINCAP) binned[(li.z >> 8) * BINCAP + p2] =
                ((unsigned)(li.z & 255) << 16) | (unsigned)lj.z;
            const unsigned p3 = bse[li.w >> 8] + atomicAdd(&cur[li.w >> 8], 1u);
            if (p3 < BINCAP) binned[(li.w >> 8) * BINCAP + p3] =
                ((unsigned)(li.w & 255) << 16) | (unsigned)lj.w;
        }
        return;
    }

    // ---------------- gemm role (even blocks) ----------------
    const int base = (bid >> 1) * 64;
    {   // stage W transposed -> bf16: wls[col][k]
        const float4* W4 = (const float4*)W;
#pragma unroll
        for (int j = 0; j < 8; ++j) {
            const int idx = tid + j * 256;   // float4 index into [128][16]
            const int k = idx >> 4;
            const int c = (idx & 15) * 4;
            const float4 v = W4[idx];
            wls[(c + 0) * WS_STRIDE + k] = (unsigned short)f2b(v.x);
            wls[(c + 1) * WS_STRIDE + k] = (unsigned short)f2b(v.y);
            wls[(c + 2) * WS_STRIDE + k] = (unsigned short)f2b(v.z);
            wls[(c + 3) * WS_STRIDE + k] = (unsigned short)f2b(v.w);
        }
    }
    {   // stage x tile as bf16 (RNE at staging — same values as before)
        const float4* x4 = (const float4*)x;
#pragma unroll
        for (int j = 0; j < 8; ++j) {
            const int idx = tid + j * 256;   // float4 index into [64][32]
            const int r = idx >> 5;
            const int kq = idx & 31;
            const int row = base + r;
            float4 v = make_float4(0.f, 0.f, 0.f, 0.f);
            if (row < N_NODES) v = x4[row * 32 + kq];
            ushort4 pb;
            pb.x = (unsigned short)f2b(v.x);
            pb.y = (unsigned short)f2b(v.y);
            pb.z = (unsigned short)f2b(v.z);
            pb.w = (unsigned short)f2b(v.w);
            *(ushort4*)&xs[r * WS_STRIDE + kq * 4] = pb;
        }
    }
    __syncthreads();
    const int w = tid >> 6, lane = tid & 63;
    const int m = lane & 15;       // A row / B-C col within tile
    const int kq = lane >> 4;      // k-chunk quad / C row-quad
    bf16x8 afr[4];
#pragma unroll
    for (int kb = 0; kb < 4; ++kb)
        afr[kb] = *(const bf16x8*)&xs[(w * 16 + m) * WS_STRIDE + kb * 32 + kq * 8];
    float sacc[4] = {0.f, 0.f, 0.f, 0.f};
    float tacc[4] = {0.f, 0.f, 0.f, 0.f};
#pragma unroll
    for (int ct = 0; ct < 4; ++ct) {          // 4 col-tiles of 16
        f4 acc = {0.f, 0.f, 0.f, 0.f};
#pragma unroll
        for (int kb = 0; kb < 4; ++kb) {
            const bf16x8 b = *(const bf16x8*)&wls[(ct * 16 + m) * WS_STRIDE + kb * 32 + kq * 8];
            acc = __builtin_amdgcn_mfma_f32_16x16x32_bf16(afr[kb], b, acc, 0, 0, 0);
        }
        const float a1 = attn[ct * 16 + m];
        const float a2 = attn[64 + ct * 16 + m];
#pragma unroll
        for (int r = 0; r < 4; ++r) {
            sacc[r] = fmaf(acc[r], a1, sacc[r]);
            tacc[r] = fmaf(acc[r], a2, tacc[r]);
            const int row = base + w * 16 + kq * 4 + r;   // C: row=(lane>>4)*4+reg
            if (row < N_NODES)
                hbuf[row * OUT_CH + ct * 16 + m] = (unsigned short)f2b(acc[r]);
        }
    }
    // reduce s/t over the 16 col-lanes (lane bits 0..3)
#pragma unroll
    for (int off = 1; off < 16; off <<= 1) {
#pragma unroll
        for (int r = 0; r < 4; ++r) {
            sacc[r] += __shfl_xor(sacc[r], off, 64);
            tacc[r] += __shfl_xor(tacc[r], off, 64);
        }
    }
    if (m == 0) {
#pragma unroll
        for (int r = 0; r < 4; ++r) {
            const int row = base + w * 16 + kq * 4 + r;
            if (row < N_NODES) { s[row] = sacc[r]; t[row] = tacc[r]; }
        }
    }
}

// One block per bin (exact R6 form): ranks via LDS atomics (zero global
// atomics), buckets in 64KB LDS, cv + count written fully COALESCED.
// s[] for the dst range LDS-staged; only scattered op is the t[src]
// gather (L2-resident). Z: one device-scope atomicAdd per block.
__global__ __launch_bounds__(1024) void weight_pass(const unsigned* __restrict__ binned,
                                                    const int* __restrict__ bin_count,
                                                    const float* __restrict__ s,
                                                    const float* __restrict__ t,
                                                    unsigned* __restrict__ cv,
                                                    int* __restrict__ count,
                                                    float* __restrict__ Zsum) {
    __shared__ unsigned bkt[256 * MAXDEG];   // 64 KB
    __shared__ unsigned cnt_l[256];
    __shared__ float s_l[256];
    __shared__ float red[16];
    const int tid = threadIdx.x;
    const int bin = blockIdx.x;
    if (tid < 256) {
        cnt_l[tid] = 0u;
        const int d = bin * 256 + tid;
        s_l[tid] = (d < N_NODES) ? s[d] : 0.0f;
    }
    __syncthreads();
    int n = bin_count[bin];
    if (n > BINCAP) n = BINCAP;
    float zs = 0.0f;
    for (int i = tid; i < n; i += 1024) {
        const unsigned e = binned[bin * BINCAP + i];
        const int dl = (int)((e >> 16) & 255u);
        const int src = (int)(e & 0xFFFFu);
        const float w = __expf(lrelu(s_l[dl] + t[src]));
        zs += w;
        const unsigned r = atomicAdd(&cnt_l[dl], 1u);
        if (r < MAXDEG) bkt[dl * MAXDEG + r] = (f2b(w) << 16) | (unsigned)src;
    }
    __syncthreads();
    {   // coalesced cv flush: 16384 u32 = 4096 uint4 (slots >= cnt are garbage,
        // never read by gather_out)
        uint4* cv4 = (uint4*)(cv + bin * (256 * MAXDEG));
        const uint4* b4 = (const uint4*)bkt;
        for (int i = tid; i < 4096; i += 1024) cv4[i] = b4[i];
    }
    if (tid < 256) {
        const int d = bin * 256 + tid;
        if (d < N_NODES) count[d] = (int)cnt_l[tid];
    }
    // block Z partial -> one global atomic
#pragma unroll
    for (int off = 32; off > 0; off >>= 1)
        zs += __shfl_down(zs, off, 64);
    if ((tid & 63) == 0) red[tid >> 6] = zs;
    __syncthreads();
    if (tid == 0) {
        float v = 0.0f;
#pragma unroll
        for (int k = 0; k < 16; ++k) v += red[k];
        atomicAdd(Zsum, v);
    }
}

// one wave per destination node; slot = lane>>3 (8 edge slots), q = lane&7
// (16-byte chunk of the 128-byte bf16 h row). R12: TWO-LEVEL software
// pipeline — both cv AND the h-row gather are issued one trip ahead, so
// trip i's FMAs consume hv loaded during trip i-1 and never wait on a
// same-trip load (the R9 measurement showed the gather loop ran ~5x above
// its byte floor at low TLP: per-trip dependent cv->h chain). Only the
// first trip pays the full chain latency. After the xor-reduce over slot
// bits every slot holds the full row sum, so slot doubles as the head
// index: 2 nontemporal float4 stores/lane cover all 8 head copies.
__global__ __launch_bounds__(256) void gather_out(const int* __restrict__ count,
                                                  const unsigned* __restrict__ cv,
                                                  const float* __restrict__ Zsum,
                                                  const unsigned short* __restrict__ hbuf,
                                                  float* __restrict__ out) {
    const int n = blockIdx.x * 4 + (threadIdx.x >> 6);  // 12500*4 = 50000 exact
    const int lane = threadIdx.x & 63;
    const int slot = lane >> 3;          // edge slot 0..7
    const int q = lane & 7;              // 16B chunk 0..7 of the h row
    const float z = 1.0f / Zsum[0];
    int cnt = count[n];
    cnt = cnt < MAXDEG ? cnt : MAXDEG;   // match weight_pass drop semantics
    const int base = n * MAXDEG;
    const uint4* h4 = (const uint4*)hbuf;
    f4 a0 = (f4)(0.0f);
    f4 a1 = (f4)(0.0f);
    // prologue: issue cv + h for trip 0 (idle slots read row 0 — harmless)
    unsigned pk = 0u;                    // src=0, weight=+0.0f for idle slots
    if (slot < cnt) pk = cv[base + slot];
    uint4 hv = h4[(int)(pk & 0xFFFFu) * 8 + q];
    for (int i = 0; i < cnt; i += 8) {
        // issue next trip's cv AND h before touching this trip's data
        unsigned pk_n = 0u;
        const int ee = i + 8 + slot;
        if (ee < cnt) pk_n = cv[base + ee];
        const uint4 hv_n = h4[(int)(pk_n & 0xFFFFu) * 8 + q];
        const float w = __uint_as_float(pk & 0xFFFF0000u);   // bf16 weight
        a0.x = fmaf(w, __uint_as_float(hv.x << 16),        a0.x);
        a0.y = fmaf(w, __uint_as_float(hv.x & 0xFFFF0000u), a0.y);
        a0.z = fmaf(w, __uint_as_float(hv.y << 16),        a0.z);
        a0.w = fmaf(w, __uint_as_float(hv.y & 0xFFFF0000u), a0.w);
        a1.x = fmaf(w, __uint_as_float(hv.z << 16),        a1.x);
        a1.y = fmaf(w, __uint_as_float(hv.z & 0xFFFF0000u), a1.y);
        a1.z = fmaf(w, __uint_as_float(hv.w << 16),        a1.z);
        a1.w = fmaf(w, __uint_as_float(hv.w & 0xFFFF0000u), a1.w);
        pk = pk_n;
        hv = hv_n;
    }
    // reduce across the 8 slots (lane bits 3,4,5); every slot ends with full sum
#pragma unroll
    for (int off = 8; off <= 32; off <<= 1) {
        a0.x += __shfl_xor(a0.x, off, 64);
        a0.y += __shfl_xor(a0.y, off, 64);
        a0.z += __shfl_xor(a0.z, off, 64);
        a0.w += __shfl_xor(a0.w, off, 64);
        a1.x += __shfl_xor(a1.x, off, 64);
        a1.y += __shfl_xor(a1.y, off, 64);
        a1.z += __shfl_xor(a1.z, off, 64);
        a1.w += __shfl_xor(a1.w, off, 64);
    }
    a0 *= z;
    a1 *= z;
    f4* out4 = (f4*)out;
    // head = slot: float4 idx slot*16 + q*2 within the 128-float4 row
    const int ob = n * 128 + slot * 16 + q * 2;
    __builtin_nontemporal_store(a0, out4 + ob);
    __builtin_nontemporal_store(a1, out4 + ob + 1);
}

extern "C" void kernel_launch(void* const* d_in, const int* in_sizes, int n_in,
                              void* d_out, int out_size, void* d_ws, size_t ws_size,
                              hipStream_t stream) {
    const float* x    = (const float*)d_in[0];
    const int*   eidx = (const int*)d_in[1];
    const float* W    = (const float*)d_in[2];
    const float* attn = (const float*)d_in[3];
    float* out = (float*)d_out;

    unsigned short* hbuf = (unsigned short*)d_ws;            // 3,200,000 bf16 (6.4 MB)
    unsigned* cv     = (unsigned*)(hbuf + N_NODES * OUT_CH); // 196*16384 u32 (12.85 MB)
    unsigned* binned = cv + NBIN * 256 * MAXDEG;             // 196*4608 u32 (3.6 MB)
    float* s         = (float*)(binned + NBIN * BINCAP);     // 50,000
    float* t         = s + N_NODES;                          // 50,000
    int* count       = (int*)(t + N_NODES);                  // 50,000
    int* bin_count   = count + N_NODES;                      // 196
    float* Zsum      = (float*)(bin_count + NBIN);           // 1

    const int4* ei4 = (const int4*)eidx;              // destinations
    const int4* ej4 = (const int4*)(eidx + N_EDGES);  // sources

    hipMemsetAsync(bin_count, 0, (NBIN + 1) * sizeof(int), stream);  // bin_count + Zsum
    gemm_bin   <<<NBLK_G + NBLK_A, 256, 0, stream>>>(x, W, attn, ei4, ej4,
                                                     hbuf, s, t, bin_count, binned);
    weight_pass<<<NBIN, 1024, 0, stream>>>(binned, bin_count, s, t, cv, count, Zsum);
    gather_out <<<N_NODES / 4, 256, 0, stream>>>(count, cv, Zsum, hbuf, out);
}